// Round 15
// baseline (228.432 us; speedup 1.0000x reference)
//
#include <hip/hip_runtime.h>
#include <cstdint>
#include <cstddef>

// MorphoGPT predictor loss, fully fused on-device. v14.
// = v13 + (a) stem LDS additive-rotation swizzle (chunk += 4*row mod 32):
// 64 lanes -> 32 distinct 16B chunks, 2-way (free) instead of 8-way bank
// conflict; source pre-permuted with the inverse. (b) mega tail roles
// consolidated (grid 2014 -> 924 blocks) so the short blocks stop cycling
// through the few non-stem CU slots. (c) prep gather x4-vectorized.

typedef __attribute__((ext_vector_type(8))) __bf16 bf16x8;
typedef __attribute__((ext_vector_type(4))) float f32x4;
typedef __attribute__((ext_vector_type(4))) unsigned short u16x4;
typedef __attribute__((ext_vector_type(2))) unsigned short u16x2;

namespace {
constexpr int S_LEN   = 448;
constexpr int N_SEQ   = 8;
constexpr int D_MODEL = 768;
constexpr int TPAD    = 3584;      // padded token rows (T = 3576)
constexpr int VS = 50000, VP = 200, VM = 400, VA = 360;
constexpr int DS_STEM = 256, DS_POS = 128, DS_MORPH = 128, DS_AFF = 128;
constexpr int VS_PAD = 50176;      // 196 * 256 ; 3136 16-row tiles
constexpr int VCHUNK = 32;         // stem vocab chunks (psum cols)
constexpr int VITERS = 3136 / VCHUNK;  // 98 16-row tiles per chunk (even)
constexpr int PERIODS = VITERS / 2;    // 49 two-tile periods
constexpr float PAD_E = (float)(VS_PAD - VS);  // exp2(0)=1 per pad row
constexpr int NVB_P = 1;
constexpr int NVB_M = 2;
constexpr float LOG2E = 1.4426950408889634f;
constexpr float LN2   = 0.6931471805599453f;
// mega-kernel role boundaries (256-thread blocks)
constexpr int B_STEM = 448;        // 14 token groups x 32 chunks
constexpr int B_P    = B_STEM + 56;    // P: 56 blocks x 64 rows
constexpr int B_M    = B_P + 112;      // M: 112 blocks x (2 chunks x 32 rows)
// aff: 2*gaff64 blocks x 64 rows; tgt: 224 blocks x 16 tokens
// fused prep kernel regions (blocks of 256 threads)
constexpr int PREP_G = TPAD * D_MODEL / 1024;         // 2688 gather blocks (x4 vec)
constexpr int PREP_T = PREP_G + 120;                  // +120 LDS-transpose tiles
constexpr int PREP_C = PREP_T + 12753;                // +12753 conv blocks
}

__device__ __forceinline__ unsigned short f2bf(float f) {
  unsigned int u = __float_as_uint(f);
  unsigned int r = (u + 0x7FFFu + ((u >> 16) & 1u)) >> 16;  // RNE
  return (unsigned short)r;
}
__device__ __forceinline__ float bf2f(unsigned short u) {
  return __uint_as_float(((unsigned int)u) << 16);
}
__device__ __forceinline__ float fexp2(float x) {
#if __has_builtin(__builtin_amdgcn_exp2f)
  return __builtin_amdgcn_exp2f(x);
#else
  return exp2f(x);
#endif
}

// ---------------- fused prep: gather_x + W-transpose (LDS tiles) + emb casts ----------------
__global__ __launch_bounds__(256) void prep_kernel(
    const float* __restrict__ tr, const int* __restrict__ hsel,
    const int* __restrict__ tsel, const int* __restrict__ asel,
    const int* __restrict__ stems, const int* __restrict__ postags,
    const int* __restrict__ morphs,
    unsigned short* __restrict__ x, int* __restrict__ tgtS, int* __restrict__ tgtP,
    int* __restrict__ tgtM, int* __restrict__ arow, int T, int Ta,
    const float* __restrict__ sW, const float* __restrict__ pW,
    const float* __restrict__ mW, const float* __restrict__ aW,
    unsigned short* __restrict__ wtS, unsigned short* __restrict__ wtP,
    unsigned short* __restrict__ wtM, unsigned short* __restrict__ wtA,
    const float* __restrict__ sE, const float* __restrict__ pE,
    const float* __restrict__ mE, const float* __restrict__ aE,
    const float* __restrict__ sb,
    unsigned short* __restrict__ dS, unsigned short* __restrict__ dP,
    unsigned short* __restrict__ dM, unsigned short* __restrict__ dA,
    float* __restrict__ bp) {
  __shared__ float tile[64][65];
  const int bid = blockIdx.x;
  const int tid = threadIdx.x;
  if (bid < PREP_G) {
    const int e4 = bid * 256 + tid;            // < TPAD*192 exact
    const size_t e = (size_t)e4 * 4;           // 4 consecutive elems, same row
    const int t = (int)(e / D_MODEL);
    const int d = (int)(e % D_MODEL);
    float4 v = make_float4(0.f, 0.f, 0.f, 0.f);
    if (t < T) {
      int idx = hsel[t];
      int n = idx / S_LEN, s = idx % S_LEN;
      v = *(const float4*)(tr + ((size_t)s * N_SEQ + n) * D_MODEL + d);
    }
    u16x4 o = { f2bf(v.x), f2bf(v.y), f2bf(v.z), f2bf(v.w) };
    *(u16x4*)(x + e) = o;
    if (e4 < T) {
      int tt = tsel[e4];
      tgtS[e4] = stems[tt]; tgtP[e4] = postags[tt]; tgtM[e4] = morphs[tt];
    }
    if (e4 < Ta) arow[e4] = tsel[asel[e4]];
  } else if (bid < PREP_T) {
    // 64x64 LDS tile transpose: W[768][DS] -> Wt[DS][768] bf16, both sides coalesced
    const int tt = bid - PREP_G;   // 0..119
    const float* W; unsigned short* Wt; int DS, kt, nt;
    if (tt < 48) { W = sW; Wt = wtS; DS = 256; kt = tt >> 2; nt = tt & 3; }
    else {
      int u = tt - 48; const int h = u / 24; u %= 24;
      kt = u >> 1; nt = u & 1; DS = 128;
      W  = (h == 0) ? pW : (h == 1) ? mW : aW;
      Wt = (h == 0) ? wtP : (h == 1) ? wtM : wtA;
    }
    const int k0 = kt * 64, n0 = nt * 64;
    const int rr = tid >> 6, cc = tid & 63;
#pragma unroll
    for (int i = 0; i < 16; ++i)
      tile[i * 4 + rr][cc] = W[(size_t)(k0 + i * 4 + rr) * DS + n0 + cc];
    __syncthreads();
#pragma unroll
    for (int i = 0; i < 16; ++i)
      Wt[(size_t)(n0 + i * 4 + rr) * D_MODEL + k0 + cc] = f2bf(tile[cc][i * 4 + rr]);
  } else {
    const size_t q = ((size_t)(bid - PREP_T) * 256 + tid) * 4;  // < 13059072
    if (q >= 13008896) {  // padded stem bias (f32, scaled by log2e)
      const size_t local = q - 13008896;  // < VS_PAD
      float4 v = make_float4(0.f, 0.f, 0.f, 0.f);
      if (local < (size_t)VS) v = *(const float4*)(sb + local);  // VS % 4 == 0
      v.x *= LOG2E; v.y *= LOG2E; v.z *= LOG2E; v.w *= LOG2E;
      *(float4*)(bp + local) = v;
      return;
    }
    const float* src; unsigned short* dst; size_t local, real;
    float sc = 1.f;
    if (q < 12845056)      { src = sE; dst = dS; local = q;            real = 12800000; sc = LOG2E; }
    else if (q < 12877824) { src = pE; dst = dP; local = q - 12845056; real = 25600; }
    else if (q < 12943360) { src = mE; dst = dM; local = q - 12877824; real = 51200; }
    else                   { src = aE; dst = dA; local = q - 12943360; real = 46080; }
    float4 v = make_float4(0.f, 0.f, 0.f, 0.f);
    if (local < real) v = *(const float4*)(src + local);
    u16x4 o = { f2bf(v.x * sc), f2bf(v.y * sc), f2bf(v.z * sc), f2bf(v.w * sc) };
    *(u16x4*)(dst + local) = o;
  }
}

// ---------------- head transform: h = LN(gelu(x @ W + b)) * g + beta ----------------
template <int NT>
__device__ __forceinline__ void head_body(
    const unsigned short* __restrict__ x, const unsigned short* __restrict__ Wt,
    const float* __restrict__ bvec, const float* __restrict__ gvec,
    const float* __restrict__ betav, unsigned short* __restrict__ hout) {
  constexpr int DS = NT * 16;
  const int lane = threadIdx.x & 63;
  const int wave = threadIdx.x >> 6;           // 0..3
  const int row0 = blockIdx.x * 64 + wave * 16;
  const int lrow = lane & 15;
  const int lk8  = (lane >> 4) * 8;

  f32x4 acc[NT];
#pragma unroll
  for (int nt = 0; nt < NT; ++nt) acc[nt] = f32x4{0.f, 0.f, 0.f, 0.f};

  const unsigned short* xrow = x + (size_t)(row0 + lrow) * D_MODEL + lk8;
#pragma unroll
  for (int ks = 0; ks < 24; ++ks) {  // K = 768 = 24 * 32
    bf16x8 a = *(const bf16x8*)(xrow + ks * 32);
#pragma unroll
    for (int nt = 0; nt < NT; ++nt) {
      bf16x8 b = *(const bf16x8*)(Wt + (size_t)(nt * 16 + lrow) * D_MODEL + ks * 32 + lk8);
      acc[nt] = __builtin_amdgcn_mfma_f32_16x16x32_bf16(a, b, acc[nt], 0, 0, 0);
    }
  }

  float bb[NT], gg[NT], be[NT];
#pragma unroll
  for (int nt = 0; nt < NT; ++nt) {
    int c = nt * 16 + lrow;
    bb[nt] = bvec[c]; gg[nt] = gvec[c]; be[nt] = betav[c];
  }
#pragma unroll
  for (int r = 0; r < 4; ++r) {
    const int row = row0 + (lane >> 4) * 4 + r;
    float vals[NT];
    float s = 0.f, s2 = 0.f;
#pragma unroll
    for (int nt = 0; nt < NT; ++nt) {
      float v = acc[nt][r] + bb[nt];
      v = 0.5f * v * (1.f + erff(v * 0.70710678118654752f));  // exact erf-gelu
      vals[nt] = v; s += v; s2 += v * v;
    }
    s  += __shfl_xor(s, 1);  s  += __shfl_xor(s, 2);  s  += __shfl_xor(s, 4);  s  += __shfl_xor(s, 8);
    s2 += __shfl_xor(s2, 1); s2 += __shfl_xor(s2, 2); s2 += __shfl_xor(s2, 4); s2 += __shfl_xor(s2, 8);
    const float mean = s * (1.f / DS);
    const float var  = s2 * (1.f / DS) - mean * mean;
    const float rstd = rsqrtf(var + 1e-12f);
#pragma unroll
    for (int nt = 0; nt < NT; ++nt) {
      float o = (vals[nt] - mean) * rstd * gg[nt] + be[nt];
      hout[(size_t)row * DS + nt * 16 + lrow] = f2bf(o);
    }
  }
}

__global__ __launch_bounds__(256, 2) void head_all_kernel(
    const unsigned short* __restrict__ x,
    const unsigned short* __restrict__ wtS, const float* __restrict__ sb,
    const float* __restrict__ sg, const float* __restrict__ sbe, unsigned short* __restrict__ hS,
    const unsigned short* __restrict__ wtP, const float* __restrict__ pb,
    const float* __restrict__ pg, const float* __restrict__ pbe, unsigned short* __restrict__ hP,
    const unsigned short* __restrict__ wtM, const float* __restrict__ mb,
    const float* __restrict__ mg, const float* __restrict__ mbe, unsigned short* __restrict__ hM,
    const unsigned short* __restrict__ wtA, const float* __restrict__ ab,
    const float* __restrict__ ag, const float* __restrict__ abe, unsigned short* __restrict__ hA) {
  if (blockIdx.y == 3)      head_body<16>(x, wtS, sb, sg, sbe, hS);
  else if (blockIdx.y == 0) head_body<8>(x, wtP, pb, pg, pbe, hP);
  else if (blockIdx.y == 1) head_body<8>(x, wtM, mb, mg, mbe, hM);
  else                      head_body<8>(x, wtA, ab, ag, abe, hA);
}

// ================= mega stats kernel (256-thread blocks, 2/CU) =================

// ---- stem role: 2 tiles per barrier period, 3 LDS buffer pairs ----
__device__ __forceinline__ void stem_role(
    const unsigned short* __restrict__ h, const unsigned short* __restrict__ emb,
    const float* __restrict__ bpad, float* __restrict__ psum,
    float* __restrict__ psum2, char* smem) {
  float* lbias = (float*)(smem + 49152);   // after 6 x 8KB tile buffers

  const int f    = blockIdx.x;             // 0..447
  const int xcd  = f & 7;
  const int m    = f >> 3;                 // 0..55
  const int bx   = m % 14;                 // token group (256 tokens)
  const int by   = (m / 14) * 8 + xcd;     // vocab chunk; 14 sharers same XCD
  const int tid  = threadIdx.x;            // 0..255
  const int lane = tid & 63;
  const int wave = tid >> 6;               // 0..3
  const int lrow = lane & 15;
  const int hi   = lane >> 4;
  const int lk8  = hi * 8;
  const int tok0 = bx * 256 + wave * 64;
  const int vbase0 = by * (VITERS * 16);

  // chunk bias -> LDS once (pre-scaled by log2e)
  for (int i = tid; i < VITERS * 16; i += 256) lbias[i] = bpad[vbase0 + i];

  // 64 tokens per wave, K=256, resident in registers/AGPRs
  bf16x8 hB[4][8];
#pragma unroll
  for (int tt = 0; tt < 4; ++tt)
#pragma unroll
    for (int ks = 0; ks < 8; ++ks)
      hB[tt][ks] = *(const bf16x8*)(h + (size_t)(tok0 + tt * 16 + lrow) * 256 + ks * 32 + lk8);

  // additive-rotation swizzle: LDS chunk c (row r) holds source chunk (c-4r)&31.
  // Read side below uses chunk (ks*4 + hi + 4*lrow)&31 -> 32 distinct chunks/wave.
  const int d0 = tid * 16;
  const int srow0 = d0 >> 9;
  const int sch  = (((d0 >> 4) & 31) - 4 * srow0) & 31;
  const int s0   = (srow0 << 9) + (sch << 4);
  const char* gsA = (const char*)emb + (size_t)vbase0 * 512 + s0;
  const char* gsB = gsA + 4096;   // rows 8-15: 4*8 == 0 (mod 32) -> same formula

  auto stage_tile = [&](int buf, int tile2) {
    __builtin_amdgcn_global_load_lds(
        (const __attribute__((address_space(1))) unsigned int*)(gsA + (size_t)tile2 * 8192),
        (__attribute__((address_space(3))) unsigned int*)(smem + buf * 8192 + wave * 1024),
        16, 0, 0);
    __builtin_amdgcn_global_load_lds(
        (const __attribute__((address_space(1))) unsigned int*)(gsB + (size_t)tile2 * 8192),
        (__attribute__((address_space(3))) unsigned int*)(smem + buf * 8192 + 4096 + wave * 1024),
        16, 0, 0);
  };

  int loff[8];
#pragma unroll
  for (int ks = 0; ks < 8; ++ks)
    loff[ks] = (lrow << 9) + ((((ks << 2) + hi + (lrow << 2)) & 31) << 4);

  float esum[4] = {0.f, 0.f, 0.f, 0.f};
  float ssum[4] = {0.f, 0.f, 0.f, 0.f};

  // prologue: pairs 0 (bufs 0,1) and 1 (bufs 2,3)
  stage_tile(0, 0); stage_tile(1, 1);
  stage_tile(2, 2); stage_tile(3, 3);
  __syncthreads();   // one-time full drain: pairs 0-1 + lbias + hB ready

#pragma unroll 1
  for (int p = 0; p < PERIODS; ++p) {
    // counted wait: pair p's 4 loads done; pair p+1's 4 may stay in flight
    if (p < PERIODS - 1) asm volatile("s_waitcnt vmcnt(4)" ::: "memory");
    else                 asm volatile("s_waitcnt vmcnt(0)" ::: "memory");
    __builtin_amdgcn_s_barrier();   // all waves' pair-p stages done; pair p-1 consumed

    const int t0 = 2 * p, t1 = 2 * p + 1;
    const int b0 = (p % 3) * 2, b1 = b0 + 1;
    const float4 bv0 = *(const float4*)(lbias + t0 * 16 + hi * 4);
    const float4 bv1 = *(const float4*)(lbias + t1 * 16 + hi * 4);

    // tile A reads (conservative waits only cover already-complete stages)
    const char* lp0 = smem + b0 * 8192;
    bf16x8 aA[8];
#pragma unroll
    for (int ks = 0; ks < 8; ++ks)
      aA[ks] = *(const bf16x8*)(lp0 + loff[ks]);

#pragma unroll
    for (int tt = 0; tt < 4; ++tt) {
      f32x4 acc = f32x4{bv0.x, bv0.y, bv0.z, bv0.w};
#pragma unroll
      for (int ks = 0; ks < 8; ++ks)
        acc = __builtin_amdgcn_mfma_f32_16x16x32_bf16(aA[ks], hB[tt][ks], acc, 0, 0, 0);
      esum[tt] += (fexp2(acc[0]) + fexp2(acc[1])) + (fexp2(acc[2]) + fexp2(acc[3]));
      ssum[tt] += (acc[0] + acc[1]) + (acc[2] + acc[3]);
    }

    // tile B reads (overlap tile-A epilogue; pair p fully staged so safe)
    const char* lp1 = smem + b1 * 8192;
    bf16x8 aB[8];
#pragma unroll
    for (int ks = 0; ks < 8; ++ks)
      aB[ks] = *(const bf16x8*)(lp1 + loff[ks]);

    // stage pair p+2 into the pair consumed at period p-1
    if (p + 2 < PERIODS) {
      const int nb = ((p + 2) % 3) * 2;
      stage_tile(nb,     2 * (p + 2));
      stage_tile(nb + 1, 2 * (p + 2) + 1);
    }

#pragma unroll
    for (int tt = 0; tt < 4; ++tt) {
      f32x4 acc = f32x4{bv1.x, bv1.y, bv1.z, bv1.w};
#pragma unroll
      for (int ks = 0; ks < 8; ++ks)
        acc = __builtin_amdgcn_mfma_f32_16x16x32_bf16(aB[ks], hB[tt][ks], acc, 0, 0, 0);
      esum[tt] += (fexp2(acc[0]) + fexp2(acc[1])) + (fexp2(acc[2]) + fexp2(acc[3]));
      ssum[tt] += (acc[0] + acc[1]) + (acc[2] + acc[3]);
    }
  }

#pragma unroll
  for (int tt = 0; tt < 4; ++tt) {
    float e = esum[tt], s = ssum[tt];
    e += __shfl_xor(e, 16); e += __shfl_xor(e, 32);
    s += __shfl_xor(s, 16); s += __shfl_xor(s, 32);
    if (hi == 0) {
      const int tok = tok0 + tt * 16 + lrow;
      psum [(size_t)tok * VCHUNK + by] = e;
      psum2[(size_t)tok * VCHUNK + by] = s * LN2;   // un-scale the smooth sum
    }
  }
}

// ---- P/M stats role (one 256-thread group; DK = 128) ----
__device__ __forceinline__ void pm_role(
    const unsigned short* __restrict__ h, const unsigned short* __restrict__ emb,
    const float* __restrict__ bias, float* __restrict__ psum,
    float* __restrict__ psum2, int V, int NVB, int vbx, int vby, char* smem) {
  const int tid = threadIdx.x;
  const int lane = tid & 63;
  const int wave4 = tid >> 6;            // 0..3
  const int colbase = vby * 256 + wave4 * 64;
  const int row0 = vbx * 32;
  const int lrow = lane & 15;
  const int hi   = lane >> 4;
  const int lk8  = hi * 8;
  float (*lds_e)[32] = (float(*)[32])smem;            // [4][32]
  float (*lds_s)[32] = (float(*)[32])(smem + 512);    // [4][32]

  bf16x8 bfr[4][4];
  float bv[4];
  bool mk[4];
#pragma unroll
  for (int nt = 0; nt < 4; ++nt) {
    int col = colbase + nt * 16 + lrow;
#pragma unroll
    for (int ks = 0; ks < 4; ++ks)
      bfr[ks][nt] = *(const bf16x8*)(emb + (size_t)col * 128 + ks * 32 + lk8);
    mk[nt] = (col < V);
    bv[nt] = mk[nt] ? bias[col] : 0.f;
  }

  f32x4 acc[2][4];
#pragma unroll
  for (int rt = 0; rt < 2; ++rt)
#pragma unroll
    for (int nt = 0; nt < 4; ++nt) acc[rt][nt] = f32x4{0.f, 0.f, 0.f, 0.f};

  const unsigned short* hrow = h + (size_t)(row0 + lrow) * 128 + lk8;
#pragma unroll
  for (int ks = 0; ks < 4; ++ks) {
#pragma unroll
    for (int rt = 0; rt < 2; ++rt) {
      bf16x8 a = *(const bf16x8*)(hrow + (size_t)rt * 16 * 128 + ks * 32);
#pragma unroll
      for (int nt = 0; nt < 4; ++nt)
        acc[rt][nt] = __builtin_amdgcn_mfma_f32_16x16x32_bf16(a, bfr[ks][nt], acc[rt][nt], 0, 0, 0);
    }
  }

#pragma unroll
  for (int rt = 0; rt < 2; ++rt)
#pragma unroll
    for (int r = 0; r < 4; ++r) {
      float e = 0.f, s = 0.f;
#pragma unroll
      for (int nt = 0; nt < 4; ++nt) {
        float v = acc[rt][nt][r] + bv[nt];
        float ev = __expf(v);
        e += mk[nt] ? ev : 0.f;
        s += mk[nt] ? v : 0.f;
      }
      e += __shfl_xor(e, 1); e += __shfl_xor(e, 2); e += __shfl_xor(e, 4); e += __shfl_xor(e, 8);
      s += __shfl_xor(s, 1); s += __shfl_xor(s, 2); s += __shfl_xor(s, 4); s += __shfl_xor(s, 8);
      if (lrow == 0) {
        lds_e[wave4][rt * 16 + hi * 4 + r] = e;
        lds_s[wave4][rt * 16 + hi * 4 + r] = s;
      }
    }
  __syncthreads();
  if (tid < 32) {
    const int rr = tid;
    float e = lds_e[0][rr] + lds_e[1][rr] + lds_e[2][rr] + lds_e[3][rr];
    float s = lds_s[0][rr] + lds_s[1][rr] + lds_s[2][rr] + lds_s[3][rr];
    const int row = row0 + rr;
    psum [(size_t)row * NVB + vby] = e;
    psum2[(size_t)row * NVB + vby] = s;
  }
  __syncthreads();  // safe back-to-back reuse of lds_e/lds_s
}

// ---- affix BCE role (one col-chunk, 64 rows = 4 x 16) ----
__device__ __forceinline__ void aff_role(
    const unsigned short* __restrict__ h, const unsigned short* __restrict__ emb,
    const float* __restrict__ bias, const int* __restrict__ asel,
    const int* __restrict__ arow, const float* __restrict__ aprob,
    float* __restrict__ partial, int Ta, int gaff64, int bx, int grp, char* smem) {
  const int tid = threadIdx.x;
  const int lane = tid & 63;
  const int wave4 = tid >> 6;
  const int colbase = grp * 256 + wave4 * 64;
  const int lrow = lane & 15;
  const int lk8  = (lane >> 4) * 8;
  float* wred = (float*)smem;   // 4 floats

  bf16x8 bfr[4][4];
  float bv[4];
  bool mk[4];
#pragma unroll
  for (int nt = 0; nt < 4; ++nt) {
    int col = colbase + nt * 16 + lrow;
#pragma unroll
    for (int ks = 0; ks < 4; ++ks)
      bfr[ks][nt] = *(const bf16x8*)(emb + (size_t)col * DS_AFF + ks * 32 + lk8);
    mk[nt] = (col < VA);
    bv[nt] = mk[nt] ? bias[col] : 0.f;
  }

  float lsum = 0.f;
  for (int it = 0; it < 4; ++it) {
    const int rb = bx * 64 + it * 16;
    const int ia = rb + lrow;
    const int srow = (ia < Ta) ? asel[ia] : 0;
    f32x4 acc[4];
#pragma unroll
    for (int nt = 0; nt < 4; ++nt) acc[nt] = f32x4{0.f, 0.f, 0.f, 0.f};
    const unsigned short* hrow = h + (size_t)srow * DS_AFF + lk8;
#pragma unroll
    for (int ks = 0; ks < 4; ++ks) {
      bf16x8 a = *(const bf16x8*)(hrow + ks * 32);
#pragma unroll
      for (int nt = 0; nt < 4; ++nt)
        acc[nt] = __builtin_amdgcn_mfma_f32_16x16x32_bf16(a, bfr[ks][nt], acc[nt], 0, 0, 0);
    }
#pragma unroll
    for (int r = 0; r < 4; ++r) {
      const int i2 = rb + (lane >> 4) * 4 + r;
      const bool live = (i2 < Ta);
      const int trow = live ? arow[i2] : 0;
#pragma unroll
      for (int nt = 0; nt < 4; ++nt) {
        if (live && mk[nt]) {
          float z = acc[nt][r] + bv[nt];
          float ta = aprob[(size_t)trow * VA + (colbase + nt * 16 + lrow)];
          lsum += fmaxf(z, 0.f) - z * ta + log1pf(__expf(-fabsf(z)));
        }
      }
    }
  }
#pragma unroll
  for (int m = 1; m < 64; m <<= 1) lsum += __shfl_xor(lsum, m);
  if (lane == 0) wred[wave4] = lsum;
  __syncthreads();
  if (tid == 0)
    partial[grp * gaff64 + bx] = wred[0] + wred[1] + wred[2] + wred[3];
}

// ---- target-logit role (16 tokens/block, all 3 heads; stem dot un-scaled by ln2) ----
__device__ __forceinline__ void tgt_role(
    const unsigned short* __restrict__ hS, const unsigned short* __restrict__ embS,
    const float* __restrict__ bS, const int* __restrict__ tgtS_,
    const unsigned short* __restrict__ hP, const unsigned short* __restrict__ embP,
    const float* __restrict__ bP, const int* __restrict__ tgtP_,
    const unsigned short* __restrict__ hM, const unsigned short* __restrict__ embM,
    const float* __restrict__ bM, const int* __restrict__ tgtM_,
    float* __restrict__ tlog, int T, int vb) {
  const int lane = threadIdx.x & 63;
  const int wave = threadIdx.x >> 6;
#pragma unroll 1
  for (int i = 0; i < 4; ++i) {
    const int t = vb * 16 + wave * 4 + i;
    if (t >= T) return;
    const int tg = tgtS_[t], tp = tgtP_[t], tm = tgtM_[t];
    u16x4 hv = *(const u16x4*)(hS + (size_t)t * 256 + lane * 4);
    u16x4 ev = *(const u16x4*)(embS + (size_t)tg * 256 + lane * 4);
    float d0 = bf2f(hv[0]) * bf2f(ev[0]) + bf2f(hv[1]) * bf2f(ev[1]) +
               bf2f(hv[2]) * bf2f(ev[2]) + bf2f(hv[3]) * bf2f(ev[3]);
    u16x2 hp = *(const u16x2*)(hP + (size_t)t * 128 + lane * 2);
    u16x2 ep = *(const u16x2*)(embP + (size_t)tp * 128 + lane * 2);
    float d1 = bf2f(hp[0]) * bf2f(ep[0]) + bf2f(hp[1]) * bf2f(ep[1]);
    u16x2 hm = *(const u16x2*)(hM + (size_t)t * 128 + lane * 2);
    u16x2 em = *(const u16x2*)(embM + (size_t)tm * 128 + lane * 2);
    float d2 = bf2f(hm[0]) * bf2f(em[0]) + bf2f(hm[1]) * bf2f(em[1]);
#pragma unroll
    for (int m = 1; m < 64; m <<= 1) {
      d0 += __shfl_xor(d0, m); d1 += __shfl_xor(d1, m); d2 += __shfl_xor(d2, m);
    }
    if (lane == 0) {
      tlog[t]            = d0 * LN2 + bS[tg];  // embS is log2e-scaled
      tlog[TPAD + t]     = d1 + bP[tp];
      tlog[2 * TPAD + t] = d2 + bM[tm];
    }
  }
}

__global__ __launch_bounds__(256, 2) void mega_stats_kernel(
    const unsigned short* __restrict__ hS, const unsigned short* __restrict__ embS,
    const float* __restrict__ bpadS, float* __restrict__ psS, float* __restrict__ ps2S,
    const unsigned short* __restrict__ hP, const unsigned short* __restrict__ embP,
    const float* __restrict__ p_bias, float* __restrict__ psP, float* __restrict__ ps2P,
    const unsigned short* __restrict__ hM, const unsigned short* __restrict__ embM,
    const float* __restrict__ m_bias, float* __restrict__ psM, float* __restrict__ ps2M,
    const unsigned short* __restrict__ hA, const unsigned short* __restrict__ embA,
    const float* __restrict__ a_bias, const int* __restrict__ asel,
    const int* __restrict__ arow, const float* __restrict__ aprob,
    float* __restrict__ affp,
    const float* __restrict__ s_bias, const int* __restrict__ tgtS,
    const int* __restrict__ tgtP, const int* __restrict__ tgtM,
    float* __restrict__ tlog, int T, int Ta, int gaff64) {
  __shared__ alignas(16) char smem_[55424];  // stem: 6x8KB tile bufs + 6.2KB bias
  const int bid = blockIdx.x;
  if (bid < B_STEM) {
    stem_role(hS, embS, bpadS, psS, ps2S, smem_);
  } else if (bid < B_P) {
    const int b = bid - B_STEM;               // 0..55, two row-groups each
    pm_role(hP, embP, p_bias, psP, ps2P, VP, NVB_P, b * 2, 0, smem_);
    pm_role(hP, embP, p_bias, psP, ps2P, VP, NVB_P, b * 2 + 1, 0, smem_);
  } else if (bid < B_M) {
    const int b = bid - B_P;                  // 0..111, both chunks each
    pm_role(hM, embM, m_bias, psM, ps2M, VM, NVB_M, b, 0, smem_);
    pm_role(hM, embM, m_bias, psM, ps2M, VM, NVB_M, b, 1, smem_);
  } else if (bid < B_M + 2 * gaff64) {
    const int b = bid - B_M;
    aff_role(hA, embA, a_bias, asel, arow, aprob, affp, Ta, gaff64, b >> 1, b & 1, smem_);
  } else {
    tgt_role(hS, embS, s_bias, tgtS, hP, embP, p_bias, tgtP,
             hM, embM, m_bias, tgtM, tlog, T, bid - B_M - 2 * gaff64);
  }
}

// ---------------- per-row combine ----------------
__global__ __launch_bounds__(256) void combine2_kernel(
    const float* __restrict__ psS, const float* __restrict__ ps2S,
    const float* __restrict__ psP, const float* __restrict__ ps2P,
    const float* __restrict__ psM, const float* __restrict__ ps2M,
    const float* __restrict__ tlog,
    float* __restrict__ nll, float* __restrict__ sm, int T) {
  const int lane = threadIdx.x & 63;
  const int wave = threadIdx.x >> 6;
  const int t = blockIdx.x * 4 + wave;
  if (t >= T) return;

  float z = 0.f, s = 0.f;
  if (lane < VCHUNK) {
    z = psS[(size_t)t * VCHUNK + lane];
    s = ps2S[(size_t)t * VCHUNK + lane];
  }
#pragma unroll
  for (int m = 1; m < 64; m <<= 1) { z += __shfl_xor(z, m); s += __shfl_xor(s, m); }
  if (lane == 0) {
    z -= PAD_E;  // pad vocab rows contributed exp2(0)=1 each
    float lz = logf(z);
    nll[t] = lz - tlog[t];
    sm[t]  = (float)VS * lz - s;

    float zP = psP[t], sP = ps2P[t];
    float lzP = logf(zP);
    nll[TPAD + t] = lzP - tlog[TPAD + t];
    sm[TPAD + t]  = (float)VP * lzP - sP;

    float zM = psM[2 * t] + psM[2 * t + 1];
    float sM = ps2M[2 * t] + ps2M[2 * t + 1];
    float lzM = logf(zM);
    nll[2 * TPAD + t] = lzM - tlog[2 * TPAD + t];
    sm[2 * TPAD + t]  = (float)VM * lzM - sM;
  }
}

// ---------------- finalize ----------------
__global__ __launch_bounds__(256) void finalize_kernel(
    const float* __restrict__ nll, const float* __restrict__ sm,
    const float* __restrict__ affp, int naff, float* __restrict__ out, int T, int Ta) {
  __shared__ float red[256];
  const int tid = threadIdx.x;
  float nll_m[3], sm_m[3];
  for (int h2 = 0; h2 < 3; ++h2) {
    float a = 0.f, b = 0.f;
    for (int t = tid; t < T; t += 256) { a += nll[h2 * TPAD + t]; b += sm[h2 * TPAD + t]; }
    red[tid] = a; __syncthreads();
    for (int s = 128; s > 0; s >>= 1) { if (tid < s) red[tid] += red[tid + s]; __syncthreads(); }
    float asum = red[0]; __syncthreads();
    red[tid] = b; __syncthreads();
    for (int s = 128; s > 0; s >>= 1) { if (tid < s) red[tid] += red[tid + s]; __syncthreads(); }
    float bsm = red[0]; __syncthreads();
    nll_m[h2] = asum / (float)T;
    sm_m[h2]  = bsm / (float)T;
  }
  float av = 0.f;
  for (int i = tid; i < naff; i += 256) av += affp[i];
  red[tid] = av; __syncthreads();
  for (int s = 128; s > 0; s >>= 1) { if (tid < s) red[tid] += red[tid + s]; __syncthreads(); }
  if (tid == 0) {
    const float Vv[3] = {(float)VS, (float)VP, (float)VM};
    for (int h2 = 0; h2 < 3; ++h2) {
      float eps_i = 0.1f / (Vv[h2] - 1.f);
      out[h2] = (1.0f - 0.1f - eps_i) * nll_m[h2] + eps_i * sm_m[h2];
      out[4 + h2] = nll_m[h2];
    }
    out[3] = red[0] / ((float)Ta * (float)VA);
  }
}

// ---------------- host launcher ----------------
extern "C" void kernel_launch(void* const* d_in, const int* in_sizes, int n_in,
                              void* d_out, int out_size, void* d_ws, size_t ws_size,
                              hipStream_t stream) {
  const float* tr      = (const float*)d_in[0];
  const float* aprob   = (const float*)d_in[1];
  const int* stems     = (const int*)d_in[2];
  const int* postags   = (const int*)d_in[3];
  const int* morphs    = (const int*)d_in[4];
  const int* hsel      = (const int*)d_in[5];
  const int* tsel      = (const int*)d_in[6];
  const int* asel      = (const int*)d_in[7];
  const float* s_emb = (const float*)d_in[8],  *s_W = (const float*)d_in[9];
  const float* s_b   = (const float*)d_in[10], *s_g = (const float*)d_in[11];
  const float* s_be  = (const float*)d_in[12], *s_bias = (const float*)d_in[13];
  const float* p_emb = (const float*)d_in[14], *p_W = (const float*)d_in[15];
  const float* p_b   = (const float*)d_in[16], *p_g = (const float*)d_in[17];
  const float* p_be  = (const float*)d_in[18], *p_bias = (const float*)d_in[19];
  const float* m_emb = (const float*)d_in[20], *m_W = (const float*)d_in[21];
  const float* m_b   = (const float*)d_in[22], *m_g = (const float*)d_in[23];
  const float* m_be  = (const float*)d_in[24], *m_bias = (const float*)d_in[25];
  const float* a_emb = (const float*)d_in[26], *a_W = (const float*)d_in[27];
  const float* a_b   = (const float*)d_in[28], *a_g = (const float*)d_in[29];
  const float* a_be  = (const float*)d_in[30], *a_bias = (const float*)d_in[31];

  const int T  = in_sizes[5];   // 3576
  const int Ta = in_sizes[7];   // ~2682

  size_t off = 0;
  auto alloc = [&](size_t nbytes) -> char* {
    char* p = (char*)d_ws + off;
    off = (off + nbytes + 255) & ~(size_t)255;
    return p;
  };
  unsigned short* x    = (unsigned short*)alloc((size_t)TPAD * D_MODEL * 2);
  unsigned short* wtS  = (unsigned short*)alloc((size_t)DS_STEM * D_MODEL * 2);
  unsigned short* wtP  = (unsigned short*)alloc((size_t)DS_POS * D_MODEL * 2);
  unsigned short* wtM  = (unsigned short*)alloc((size_t)DS_MORPH * D_MODEL * 2);
  unsigned short* wtA  = (unsigned short*)alloc((size_t)DS_AFF * D_MODEL * 2);
  unsigned short* embS = (unsigned short*)alloc((size_t)VS_PAD * DS_STEM * 2);
  unsigned short* embP = (unsigned short*)alloc((size_t)256 * DS_POS * 2);
  unsigned short* embM = (unsigned short*)alloc((size_t)512 * DS_MORPH * 2);
  unsigned short* embA = (unsigned short*)alloc((size_t)512 * DS_AFF * 2);
  unsigned short* hS   = (unsigned short*)alloc((size_t)TPAD * DS_STEM * 2);
  unsigned short* hP   = (unsigned short*)alloc((size_t)TPAD * DS_POS * 2);
  unsigned short* hM   = (unsigned short*)alloc((size_t)TPAD * DS_MORPH * 2);
  unsigned short* hA   = (unsigned short*)alloc((size_t)TPAD * DS_AFF * 2);
  float* bpadS = (float*)alloc((size_t)VS_PAD * 4);
  float* psS   = (float*)alloc((size_t)TPAD * VCHUNK * 4);
  float* ps2S  = (float*)alloc((size_t)TPAD * VCHUNK * 4);
  float* psP   = (float*)alloc((size_t)TPAD * NVB_P * 4);
  float* ps2P  = (float*)alloc((size_t)TPAD * NVB_P * 4);
  float* psM   = (float*)alloc((size_t)TPAD * NVB_M * 4);
  float* ps2M  = (float*)alloc((size_t)TPAD * NVB_M * 4);
  float* tlog  = (float*)alloc((size_t)3 * TPAD * 4);
  int*   tgtS  = (int*)alloc((size_t)TPAD * 4);
  int*   tgtP  = (int*)alloc((size_t)TPAD * 4);
  int*   tgtM  = (int*)alloc((size_t)TPAD * 4);
  int*   arow  = (int*)alloc((size_t)TPAD * 4);
  float* nllb  = (float*)alloc((size_t)3 * TPAD * 4);
  float* smb   = (float*)alloc((size_t)3 * TPAD * 4);
  float* affp  = (float*)alloc(2048);
  (void)ws_size; (void)n_in; (void)out_size;

  const int gaff64 = (Ta + 63) / 64;     // ~42
  const int tgtb   = (T + 15) / 16;      // 224

  // 1. fused prep: gather(x4) + LDS-tiled W transposes + emb casts
  prep_kernel<<<PREP_C, 256, 0, stream>>>(
      tr, hsel, tsel, asel, stems, postags, morphs, x, tgtS, tgtP, tgtM, arow, T, Ta,
      s_W, p_W, m_W, a_W, wtS, wtP, wtM, wtA,
      s_emb, p_emb, m_emb, a_emb, s_bias, embS, embP, embM, embA, bpadS);
  // 2. all head transforms in one dispatch (256-thread blocks, 64 rows each)
  head_all_kernel<<<dim3(TPAD / 64, 4), 256, 0, stream>>>(
      x, wtS, s_b, s_g, s_be, hS, wtP, p_b, p_g, p_be, hP,
      wtM, m_b, m_g, m_be, hM, wtA, a_b, a_g, a_be, hA);
  // 3. mega: stem stats (rot-swizzle) + consolidated P/M/aff/tgt roles
  mega_stats_kernel<<<B_M + 2 * gaff64 + tgtb, 256, 0, stream>>>(
      hS, embS, bpadS, psS, ps2S,
      hP, embP, p_bias, psP, ps2P,
      hM, embM, m_bias, psM, ps2M,
      hA, embA, a_bias, asel, arow, aprob, affp,
      s_bias, tgtS, tgtP, tgtM, tlog, T, Ta, gaff64);
  // 4. per-row combine + final reduction
  combine2_kernel<<<(T + 3) / 4, 256, 0, stream>>>(psS, ps2S, psP, ps2P, psM, ps2M, tlog, nllb, smb, T);
  finalize_kernel<<<1, 256, 0, stream>>>(nllb, smb, affp, gaff64 * 2, (float*)d_out, T, Ta);
}

// Round 16
// 218.574 us; speedup vs baseline: 1.0451x; 1.0451x over previous
//
#include <hip/hip_runtime.h>
#include <cstdint>
#include <cstddef>

// MorphoGPT predictor loss, fully fused on-device. v15.
// = v13 (verified 221us: XOR-swizzled stem, unconsolidated tail) + v14's
// independent prep-gather x4 vectorization. The v14 rotation swizzle and
// tail consolidation are REVERTED (regression isolated to that bundle;
// SQ_LDS_BANK_CONFLICT proved bit-identical across swizzles -> structural
// b128 serialization, not fixable by swizzling).

typedef __attribute__((ext_vector_type(8))) __bf16 bf16x8;
typedef __attribute__((ext_vector_type(4))) float f32x4;
typedef __attribute__((ext_vector_type(4))) unsigned short u16x4;
typedef __attribute__((ext_vector_type(2))) unsigned short u16x2;

namespace {
constexpr int S_LEN   = 448;
constexpr int N_SEQ   = 8;
constexpr int D_MODEL = 768;
constexpr int TPAD    = 3584;      // padded token rows (T = 3576)
constexpr int VS = 50000, VP = 200, VM = 400, VA = 360;
constexpr int DS_STEM = 256, DS_POS = 128, DS_MORPH = 128, DS_AFF = 128;
constexpr int VS_PAD = 50176;      // 196 * 256 ; 3136 16-row tiles
constexpr int VCHUNK = 32;         // stem vocab chunks (psum cols)
constexpr int VITERS = 3136 / VCHUNK;  // 98 16-row tiles per chunk (even)
constexpr int PERIODS = VITERS / 2;    // 49 two-tile periods
constexpr float PAD_E = (float)(VS_PAD - VS);  // exp2(0)=1 per pad row
constexpr int NVB_P = 1;
constexpr int NVB_M = 2;
constexpr float LOG2E = 1.4426950408889634f;
constexpr float LN2   = 0.6931471805599453f;
// mega-kernel role boundaries (256-thread blocks)
constexpr int B_STEM = 448;        // 14 token groups x 32 chunks
constexpr int B_P    = B_STEM + 112;
constexpr int B_M    = B_P + 224;
// fused prep kernel regions (blocks of 256 threads)
constexpr int PREP_G = TPAD * D_MODEL / 1024;         // 2688 gather blocks (x4 vec)
constexpr int PREP_T = PREP_G + 120;                  // +120 LDS-transpose tiles
constexpr int PREP_C = PREP_T + 12753;                // +12753 conv blocks
}

__device__ __forceinline__ unsigned short f2bf(float f) {
  unsigned int u = __float_as_uint(f);
  unsigned int r = (u + 0x7FFFu + ((u >> 16) & 1u)) >> 16;  // RNE
  return (unsigned short)r;
}
__device__ __forceinline__ float bf2f(unsigned short u) {
  return __uint_as_float(((unsigned int)u) << 16);
}
__device__ __forceinline__ float fexp2(float x) {
#if __has_builtin(__builtin_amdgcn_exp2f)
  return __builtin_amdgcn_exp2f(x);
#else
  return exp2f(x);
#endif
}

// ---------------- fused prep: gather_x(x4) + W-transpose (LDS tiles) + emb casts ----------------
__global__ __launch_bounds__(256) void prep_kernel(
    const float* __restrict__ tr, const int* __restrict__ hsel,
    const int* __restrict__ tsel, const int* __restrict__ asel,
    const int* __restrict__ stems, const int* __restrict__ postags,
    const int* __restrict__ morphs,
    unsigned short* __restrict__ x, int* __restrict__ tgtS, int* __restrict__ tgtP,
    int* __restrict__ tgtM, int* __restrict__ arow, int T, int Ta,
    const float* __restrict__ sW, const float* __restrict__ pW,
    const float* __restrict__ mW, const float* __restrict__ aW,
    unsigned short* __restrict__ wtS, unsigned short* __restrict__ wtP,
    unsigned short* __restrict__ wtM, unsigned short* __restrict__ wtA,
    const float* __restrict__ sE, const float* __restrict__ pE,
    const float* __restrict__ mE, const float* __restrict__ aE,
    const float* __restrict__ sb,
    unsigned short* __restrict__ dS, unsigned short* __restrict__ dP,
    unsigned short* __restrict__ dM, unsigned short* __restrict__ dA,
    float* __restrict__ bp) {
  __shared__ float tile[64][65];
  const int bid = blockIdx.x;
  const int tid = threadIdx.x;
  if (bid < PREP_G) {
    const int e4 = bid * 256 + tid;            // < TPAD*192 exact
    const size_t e = (size_t)e4 * 4;           // 4 consecutive elems, same row
    const int t = (int)(e / D_MODEL);
    const int d = (int)(e % D_MODEL);
    float4 v = make_float4(0.f, 0.f, 0.f, 0.f);
    if (t < T) {
      int idx = hsel[t];
      int n = idx / S_LEN, s = idx % S_LEN;
      v = *(const float4*)(tr + ((size_t)s * N_SEQ + n) * D_MODEL + d);
    }
    u16x4 o = { f2bf(v.x), f2bf(v.y), f2bf(v.z), f2bf(v.w) };
    *(u16x4*)(x + e) = o;
    if (e4 < T) {
      int tt = tsel[e4];
      tgtS[e4] = stems[tt]; tgtP[e4] = postags[tt]; tgtM[e4] = morphs[tt];
    }
    if (e4 < Ta) arow[e4] = tsel[asel[e4]];
  } else if (bid < PREP_T) {
    // 64x64 LDS tile transpose: W[768][DS] -> Wt[DS][768] bf16, both sides coalesced
    const int tt = bid - PREP_G;   // 0..119
    const float* W; unsigned short* Wt; int DS, kt, nt;
    if (tt < 48) { W = sW; Wt = wtS; DS = 256; kt = tt >> 2; nt = tt & 3; }
    else {
      int u = tt - 48; const int h = u / 24; u %= 24;
      kt = u >> 1; nt = u & 1; DS = 128;
      W  = (h == 0) ? pW : (h == 1) ? mW : aW;
      Wt = (h == 0) ? wtP : (h == 1) ? wtM : wtA;
    }
    const int k0 = kt * 64, n0 = nt * 64;
    const int rr = tid >> 6, cc = tid & 63;
#pragma unroll
    for (int i = 0; i < 16; ++i)
      tile[i * 4 + rr][cc] = W[(size_t)(k0 + i * 4 + rr) * DS + n0 + cc];
    __syncthreads();
#pragma unroll
    for (int i = 0; i < 16; ++i)
      Wt[(size_t)(n0 + i * 4 + rr) * D_MODEL + k0 + cc] = f2bf(tile[cc][i * 4 + rr]);
  } else {
    const size_t q = ((size_t)(bid - PREP_T) * 256 + tid) * 4;  // < 13059072
    if (q >= 13008896) {  // padded stem bias (f32, scaled by log2e)
      const size_t local = q - 13008896;  // < VS_PAD
      float4 v = make_float4(0.f, 0.f, 0.f, 0.f);
      if (local < (size_t)VS) v = *(const float4*)(sb + local);  // VS % 4 == 0
      v.x *= LOG2E; v.y *= LOG2E; v.z *= LOG2E; v.w *= LOG2E;
      *(float4*)(bp + local) = v;
      return;
    }
    const float* src; unsigned short* dst; size_t local, real;
    float sc = 1.f;
    if (q < 12845056)      { src = sE; dst = dS; local = q;            real = 12800000; sc = LOG2E; }
    else if (q < 12877824) { src = pE; dst = dP; local = q - 12845056; real = 25600; }
    else if (q < 12943360) { src = mE; dst = dM; local = q - 12877824; real = 51200; }
    else                   { src = aE; dst = dA; local = q - 12943360; real = 46080; }
    float4 v = make_float4(0.f, 0.f, 0.f, 0.f);
    if (local < real) v = *(const float4*)(src + local);
    u16x4 o = { f2bf(v.x * sc), f2bf(v.y * sc), f2bf(v.z * sc), f2bf(v.w * sc) };
    *(u16x4*)(dst + local) = o;
  }
}

// ---------------- head transform: h = LN(gelu(x @ W + b)) * g + beta ----------------
// 256-thread blocks: 4 waves x 16 rows = 64 rows/block.
template <int NT>
__device__ __forceinline__ void head_body(
    const unsigned short* __restrict__ x, const unsigned short* __restrict__ Wt,
    const float* __restrict__ bvec, const float* __restrict__ gvec,
    const float* __restrict__ betav, unsigned short* __restrict__ hout) {
  constexpr int DS = NT * 16;
  const int lane = threadIdx.x & 63;
  const int wave = threadIdx.x >> 6;           // 0..3
  const int row0 = blockIdx.x * 64 + wave * 16;
  const int lrow = lane & 15;
  const int lk8  = (lane >> 4) * 8;

  f32x4 acc[NT];
#pragma unroll
  for (int nt = 0; nt < NT; ++nt) acc[nt] = f32x4{0.f, 0.f, 0.f, 0.f};

  const unsigned short* xrow = x + (size_t)(row0 + lrow) * D_MODEL + lk8;
#pragma unroll
  for (int ks = 0; ks < 24; ++ks) {  // K = 768 = 24 * 32
    bf16x8 a = *(const bf16x8*)(xrow + ks * 32);
#pragma unroll
    for (int nt = 0; nt < NT; ++nt) {
      bf16x8 b = *(const bf16x8*)(Wt + (size_t)(nt * 16 + lrow) * D_MODEL + ks * 32 + lk8);
      acc[nt] = __builtin_amdgcn_mfma_f32_16x16x32_bf16(a, b, acc[nt], 0, 0, 0);
    }
  }

  float bb[NT], gg[NT], be[NT];
#pragma unroll
  for (int nt = 0; nt < NT; ++nt) {
    int c = nt * 16 + lrow;
    bb[nt] = bvec[c]; gg[nt] = gvec[c]; be[nt] = betav[c];
  }
#pragma unroll
  for (int r = 0; r < 4; ++r) {
    const int row = row0 + (lane >> 4) * 4 + r;
    float vals[NT];
    float s = 0.f, s2 = 0.f;
#pragma unroll
    for (int nt = 0; nt < NT; ++nt) {
      float v = acc[nt][r] + bb[nt];
      v = 0.5f * v * (1.f + erff(v * 0.70710678118654752f));  // exact erf-gelu
      vals[nt] = v; s += v; s2 += v * v;
    }
    s  += __shfl_xor(s, 1);  s  += __shfl_xor(s, 2);  s  += __shfl_xor(s, 4);  s  += __shfl_xor(s, 8);
    s2 += __shfl_xor(s2, 1); s2 += __shfl_xor(s2, 2); s2 += __shfl_xor(s2, 4); s2 += __shfl_xor(s2, 8);
    const float mean = s * (1.f / DS);
    const float var  = s2 * (1.f / DS) - mean * mean;
    const float rstd = rsqrtf(var + 1e-12f);
#pragma unroll
    for (int nt = 0; nt < NT; ++nt) {
      float o = (vals[nt] - mean) * rstd * gg[nt] + be[nt];
      hout[(size_t)row * DS + nt * 16 + lrow] = f2bf(o);
    }
  }
}

__global__ __launch_bounds__(256, 2) void head_all_kernel(
    const unsigned short* __restrict__ x,
    const unsigned short* __restrict__ wtS, const float* __restrict__ sb,
    const float* __restrict__ sg, const float* __restrict__ sbe, unsigned short* __restrict__ hS,
    const unsigned short* __restrict__ wtP, const float* __restrict__ pb,
    const float* __restrict__ pg, const float* __restrict__ pbe, unsigned short* __restrict__ hP,
    const unsigned short* __restrict__ wtM, const float* __restrict__ mb,
    const float* __restrict__ mg, const float* __restrict__ mbe, unsigned short* __restrict__ hM,
    const unsigned short* __restrict__ wtA, const float* __restrict__ ab,
    const float* __restrict__ ag, const float* __restrict__ abe, unsigned short* __restrict__ hA) {
  if (blockIdx.y == 3)      head_body<16>(x, wtS, sb, sg, sbe, hS);
  else if (blockIdx.y == 0) head_body<8>(x, wtP, pb, pg, pbe, hP);
  else if (blockIdx.y == 1) head_body<8>(x, wtM, mb, mg, mbe, hM);
  else                      head_body<8>(x, wtA, ab, ag, abe, hA);
}

// ================= mega stats kernel (256-thread blocks, 2/CU) =================

// ---- stem role: 2 tiles per barrier period, 3 LDS buffer pairs ----
__device__ __forceinline__ void stem_role(
    const unsigned short* __restrict__ h, const unsigned short* __restrict__ emb,
    const float* __restrict__ bpad, float* __restrict__ psum,
    float* __restrict__ psum2, char* smem) {
  float* lbias = (float*)(smem + 49152);   // after 6 x 8KB tile buffers

  const int f    = blockIdx.x;             // 0..447
  const int xcd  = f & 7;
  const int m    = f >> 3;                 // 0..55
  const int bx   = m % 14;                 // token group (256 tokens)
  const int by   = (m / 14) * 8 + xcd;     // vocab chunk; 14 sharers same XCD
  const int tid  = threadIdx.x;            // 0..255
  const int lane = tid & 63;
  const int wave = tid >> 6;               // 0..3
  const int lrow = lane & 15;
  const int hi   = lane >> 4;
  const int lk8  = hi * 8;
  const int tok0 = bx * 256 + wave * 64;
  const int vbase0 = by * (VITERS * 16);

  // chunk bias -> LDS once (pre-scaled by log2e)
  for (int i = tid; i < VITERS * 16; i += 256) lbias[i] = bpad[vbase0 + i];

  // 64 tokens per wave, K=256, resident in registers/AGPRs
  bf16x8 hB[4][8];
#pragma unroll
  for (int tt = 0; tt < 4; ++tt)
#pragma unroll
    for (int ks = 0; ks < 8; ++ks)
      hB[tt][ks] = *(const bf16x8*)(h + (size_t)(tok0 + tt * 16 + lrow) * 256 + ks * 32 + lk8);

  // staging source: pre-swizzled so linear LDS dest + swizzled ds_read = identity
  const int d0 = tid * 16;
  const int s0 = d0 ^ (((d0 >> 9) & 7) << 4);
  const char* gsA = (const char*)emb + (size_t)vbase0 * 512 + s0;
  const char* gsB = gsA + 4096;   // rows 8-15: same low-3 row bits -> same XOR

  auto stage_tile = [&](int buf, int tile2) {
    __builtin_amdgcn_global_load_lds(
        (const __attribute__((address_space(1))) unsigned int*)(gsA + (size_t)tile2 * 8192),
        (__attribute__((address_space(3))) unsigned int*)(smem + buf * 8192 + wave * 1024),
        16, 0, 0);
    __builtin_amdgcn_global_load_lds(
        (const __attribute__((address_space(1))) unsigned int*)(gsB + (size_t)tile2 * 8192),
        (__attribute__((address_space(3))) unsigned int*)(smem + buf * 8192 + 4096 + wave * 1024),
        16, 0, 0);
  };

  int loff[8];
#pragma unroll
  for (int ks = 0; ks < 8; ++ks)
    loff[ks] = (lrow * 512 + ks * 64 + hi * 16) ^ ((lrow & 7) << 4);

  float esum[4] = {0.f, 0.f, 0.f, 0.f};
  float ssum[4] = {0.f, 0.f, 0.f, 0.f};

  // prologue: pairs 0 (bufs 0,1) and 1 (bufs 2,3)
  stage_tile(0, 0); stage_tile(1, 1);
  stage_tile(2, 2); stage_tile(3, 3);
  __syncthreads();   // one-time full drain: pairs 0-1 + lbias + hB ready

#pragma unroll 1
  for (int p = 0; p < PERIODS; ++p) {
    // counted wait: pair p's 4 loads done; pair p+1's 4 may stay in flight
    if (p < PERIODS - 1) asm volatile("s_waitcnt vmcnt(4)" ::: "memory");
    else                 asm volatile("s_waitcnt vmcnt(0)" ::: "memory");
    __builtin_amdgcn_s_barrier();   // all waves' pair-p stages done; pair p-1 consumed

    const int t0 = 2 * p, t1 = 2 * p + 1;
    const int b0 = (p % 3) * 2, b1 = b0 + 1;
    const float4 bv0 = *(const float4*)(lbias + t0 * 16 + hi * 4);
    const float4 bv1 = *(const float4*)(lbias + t1 * 16 + hi * 4);

    // tile A reads (conservative waits only cover already-complete stages)
    const char* lp0 = smem + b0 * 8192;
    bf16x8 aA[8];
#pragma unroll
    for (int ks = 0; ks < 8; ++ks)
      aA[ks] = *(const bf16x8*)(lp0 + loff[ks]);

#pragma unroll
    for (int tt = 0; tt < 4; ++tt) {
      f32x4 acc = f32x4{bv0.x, bv0.y, bv0.z, bv0.w};
#pragma unroll
      for (int ks = 0; ks < 8; ++ks)
        acc = __builtin_amdgcn_mfma_f32_16x16x32_bf16(aA[ks], hB[tt][ks], acc, 0, 0, 0);
      esum[tt] += (fexp2(acc[0]) + fexp2(acc[1])) + (fexp2(acc[2]) + fexp2(acc[3]));
      ssum[tt] += (acc[0] + acc[1]) + (acc[2] + acc[3]);
    }

    // tile B reads (overlap tile-A epilogue; pair p fully staged so safe)
    const char* lp1 = smem + b1 * 8192;
    bf16x8 aB[8];
#pragma unroll
    for (int ks = 0; ks < 8; ++ks)
      aB[ks] = *(const bf16x8*)(lp1 + loff[ks]);

    // stage pair p+2 into the pair consumed at period p-1
    if (p + 2 < PERIODS) {
      const int nb = ((p + 2) % 3) * 2;
      stage_tile(nb,     2 * (p + 2));
      stage_tile(nb + 1, 2 * (p + 2) + 1);
    }

#pragma unroll
    for (int tt = 0; tt < 4; ++tt) {
      f32x4 acc = f32x4{bv1.x, bv1.y, bv1.z, bv1.w};
#pragma unroll
      for (int ks = 0; ks < 8; ++ks)
        acc = __builtin_amdgcn_mfma_f32_16x16x32_bf16(aB[ks], hB[tt][ks], acc, 0, 0, 0);
      esum[tt] += (fexp2(acc[0]) + fexp2(acc[1])) + (fexp2(acc[2]) + fexp2(acc[3]));
      ssum[tt] += (acc[0] + acc[1]) + (acc[2] + acc[3]);
    }
  }

#pragma unroll
  for (int tt = 0; tt < 4; ++tt) {
    float e = esum[tt], s = ssum[tt];
    e += __shfl_xor(e, 16); e += __shfl_xor(e, 32);
    s += __shfl_xor(s, 16); s += __shfl_xor(s, 32);
    if (hi == 0) {
      const int tok = tok0 + tt * 16 + lrow;
      psum [(size_t)tok * VCHUNK + by] = e;
      psum2[(size_t)tok * VCHUNK + by] = s * LN2;   // un-scale the smooth sum
    }
  }
}

// ---- P/M stats role (one 256-thread group; DK = 128) ----
__device__ __forceinline__ void pm_role(
    const unsigned short* __restrict__ h, const unsigned short* __restrict__ emb,
    const float* __restrict__ bias, float* __restrict__ psum,
    float* __restrict__ psum2, int V, int NVB, int vbx, int vby, char* smem) {
  const int tid = threadIdx.x;
  const int lane = tid & 63;
  const int wave4 = tid >> 6;            // 0..3
  const int colbase = vby * 256 + wave4 * 64;
  const int row0 = vbx * 32;
  const int lrow = lane & 15;
  const int hi   = lane >> 4;
  const int lk8  = hi * 8;
  float (*lds_e)[32] = (float(*)[32])smem;            // [4][32]
  float (*lds_s)[32] = (float(*)[32])(smem + 512);    // [4][32]

  bf16x8 bfr[4][4];
  float bv[4];
  bool mk[4];
#pragma unroll
  for (int nt = 0; nt < 4; ++nt) {
    int col = colbase + nt * 16 + lrow;
#pragma unroll
    for (int ks = 0; ks < 4; ++ks)
      bfr[ks][nt] = *(const bf16x8*)(emb + (size_t)col * 128 + ks * 32 + lk8);
    mk[nt] = (col < V);
    bv[nt] = mk[nt] ? bias[col] : 0.f;
  }

  f32x4 acc[2][4];
#pragma unroll
  for (int rt = 0; rt < 2; ++rt)
#pragma unroll
    for (int nt = 0; nt < 4; ++nt) acc[rt][nt] = f32x4{0.f, 0.f, 0.f, 0.f};

  const unsigned short* hrow = h + (size_t)(row0 + lrow) * 128 + lk8;
#pragma unroll
  for (int ks = 0; ks < 4; ++ks) {
#pragma unroll
    for (int rt = 0; rt < 2; ++rt) {
      bf16x8 a = *(const bf16x8*)(hrow + (size_t)rt * 16 * 128 + ks * 32);
#pragma unroll
      for (int nt = 0; nt < 4; ++nt)
        acc[rt][nt] = __builtin_amdgcn_mfma_f32_16x16x32_bf16(a, bfr[ks][nt], acc[rt][nt], 0, 0, 0);
    }
  }

#pragma unroll
  for (int rt = 0; rt < 2; ++rt)
#pragma unroll
    for (int r = 0; r < 4; ++r) {
      float e = 0.f, s = 0.f;
#pragma unroll
      for (int nt = 0; nt < 4; ++nt) {
        float v = acc[rt][nt][r] + bv[nt];
        float ev = __expf(v);
        e += mk[nt] ? ev : 0.f;
        s += mk[nt] ? v : 0.f;
      }
      e += __shfl_xor(e, 1); e += __shfl_xor(e, 2); e += __shfl_xor(e, 4); e += __shfl_xor(e, 8);
      s += __shfl_xor(s, 1); s += __shfl_xor(s, 2); s += __shfl_xor(s, 4); s += __shfl_xor(s, 8);
      if (lrow == 0) {
        lds_e[wave4][rt * 16 + hi * 4 + r] = e;
        lds_s[wave4][rt * 16 + hi * 4 + r] = s;
      }
    }
  __syncthreads();
  if (tid < 32) {
    const int rr = tid;
    float e = lds_e[0][rr] + lds_e[1][rr] + lds_e[2][rr] + lds_e[3][rr];
    float s = lds_s[0][rr] + lds_s[1][rr] + lds_s[2][rr] + lds_s[3][rr];
    const int row = row0 + rr;
    psum [(size_t)row * NVB + vby] = e;
    psum2[(size_t)row * NVB + vby] = s;
  }
}

// ---- affix BCE role (one col-chunk, 16 rows) ----
__device__ __forceinline__ void aff_role(
    const unsigned short* __restrict__ h, const unsigned short* __restrict__ emb,
    const float* __restrict__ bias, const int* __restrict__ asel,
    const int* __restrict__ arow, const float* __restrict__ aprob,
    float* __restrict__ partial, int Ta, int gaff, int bx, int grp, char* smem) {
  const int tid = threadIdx.x;
  const int lane = tid & 63;
  const int wave4 = tid >> 6;
  const int colbase = grp * 256 + wave4 * 64;
  const int lrow = lane & 15;
  const int lk8  = (lane >> 4) * 8;
  float* wred = (float*)smem;   // 4 floats

  bf16x8 bfr[4][4];
  float bv[4];
  bool mk[4];
#pragma unroll
  for (int nt = 0; nt < 4; ++nt) {
    int col = colbase + nt * 16 + lrow;
#pragma unroll
    for (int ks = 0; ks < 4; ++ks)
      bfr[ks][nt] = *(const bf16x8*)(emb + (size_t)col * DS_AFF + ks * 32 + lk8);
    mk[nt] = (col < VA);
    bv[nt] = mk[nt] ? bias[col] : 0.f;
  }

  float lsum = 0.f;
  {
    const int rb = bx * 16;
    const int ia = rb + lrow;
    const int srow = (ia < Ta) ? asel[ia] : 0;
    f32x4 acc[4];
#pragma unroll
    for (int nt = 0; nt < 4; ++nt) acc[nt] = f32x4{0.f, 0.f, 0.f, 0.f};
    const unsigned short* hrow = h + (size_t)srow * DS_AFF + lk8;
#pragma unroll
    for (int ks = 0; ks < 4; ++ks) {
      bf16x8 a = *(const bf16x8*)(hrow + ks * 32);
#pragma unroll
      for (int nt = 0; nt < 4; ++nt)
        acc[nt] = __builtin_amdgcn_mfma_f32_16x16x32_bf16(a, bfr[ks][nt], acc[nt], 0, 0, 0);
    }
#pragma unroll
    for (int r = 0; r < 4; ++r) {
      const int i2 = rb + (lane >> 4) * 4 + r;
      const bool live = (i2 < Ta);
      const int trow = live ? arow[i2] : 0;
#pragma unroll
      for (int nt = 0; nt < 4; ++nt) {
        if (live && mk[nt]) {
          float z = acc[nt][r] + bv[nt];
          float ta = aprob[(size_t)trow * VA + (colbase + nt * 16 + lrow)];
          lsum += fmaxf(z, 0.f) - z * ta + log1pf(__expf(-fabsf(z)));
        }
      }
    }
  }
#pragma unroll
  for (int m = 1; m < 64; m <<= 1) lsum += __shfl_xor(lsum, m);
  if (lane == 0) wred[wave4] = lsum;
  __syncthreads();
  if (tid == 0)
    partial[grp * gaff + bx] = wred[0] + wred[1] + wred[2] + wred[3];
}

// ---- target-logit role (4 tokens/block, all 3 heads; stem dot un-scaled by ln2) ----
__device__ __forceinline__ void tgt_role(
    const unsigned short* __restrict__ hS, const unsigned short* __restrict__ embS,
    const float* __restrict__ bS, const int* __restrict__ tgtS_,
    const unsigned short* __restrict__ hP, const unsigned short* __restrict__ embP,
    const float* __restrict__ bP, const int* __restrict__ tgtP_,
    const unsigned short* __restrict__ hM, const unsigned short* __restrict__ embM,
    const float* __restrict__ bM, const int* __restrict__ tgtM_,
    float* __restrict__ tlog, int T, int vb) {
  const int lane = threadIdx.x & 63;
  const int wave = threadIdx.x >> 6;
  const int t = vb * 4 + wave;
  if (t >= T) return;
  const int tg = tgtS_[t], tp = tgtP_[t], tm = tgtM_[t];
  u16x4 hv = *(const u16x4*)(hS + (size_t)t * 256 + lane * 4);
  u16x4 ev = *(const u16x4*)(embS + (size_t)tg * 256 + lane * 4);
  float d0 = bf2f(hv[0]) * bf2f(ev[0]) + bf2f(hv[1]) * bf2f(ev[1]) +
             bf2f(hv[2]) * bf2f(ev[2]) + bf2f(hv[3]) * bf2f(ev[3]);
  u16x2 hp = *(const u16x2*)(hP + (size_t)t * 128 + lane * 2);
  u16x2 ep = *(const u16x2*)(embP + (size_t)tp * 128 + lane * 2);
  float d1 = bf2f(hp[0]) * bf2f(ep[0]) + bf2f(hp[1]) * bf2f(ep[1]);
  u16x2 hm = *(const u16x2*)(hM + (size_t)t * 128 + lane * 2);
  u16x2 em = *(const u16x2*)(embM + (size_t)tm * 128 + lane * 2);
  float d2 = bf2f(hm[0]) * bf2f(em[0]) + bf2f(hm[1]) * bf2f(em[1]);
#pragma unroll
  for (int m = 1; m < 64; m <<= 1) {
    d0 += __shfl_xor(d0, m); d1 += __shfl_xor(d1, m); d2 += __shfl_xor(d2, m);
  }
  if (lane == 0) {
    tlog[t]            = d0 * LN2 + bS[tg];  // embS is log2e-scaled
    tlog[TPAD + t]     = d1 + bP[tp];
    tlog[2 * TPAD + t] = d2 + bM[tm];
  }
}

__global__ __launch_bounds__(256, 2) void mega_stats_kernel(
    const unsigned short* __restrict__ hS, const unsigned short* __restrict__ embS,
    const float* __restrict__ bpadS, float* __restrict__ psS, float* __restrict__ ps2S,
    const unsigned short* __restrict__ hP, const unsigned short* __restrict__ embP,
    const float* __restrict__ p_bias, float* __restrict__ psP, float* __restrict__ ps2P,
    const unsigned short* __restrict__ hM, const unsigned short* __restrict__ embM,
    const float* __restrict__ m_bias, float* __restrict__ psM, float* __restrict__ ps2M,
    const unsigned short* __restrict__ hA, const unsigned short* __restrict__ embA,
    const float* __restrict__ a_bias, const int* __restrict__ asel,
    const int* __restrict__ arow, const float* __restrict__ aprob,
    float* __restrict__ affp,
    const float* __restrict__ s_bias, const int* __restrict__ tgtS,
    const int* __restrict__ tgtP, const int* __restrict__ tgtM,
    float* __restrict__ tlog, int T, int Ta, int gaff) {
  __shared__ alignas(16) char smem_[55424];  // stem: 6x8KB tile bufs + 6.2KB bias
  const int bid = blockIdx.x;
  if (bid < B_STEM) {
    stem_role(hS, embS, bpadS, psS, ps2S, smem_);
  } else if (bid < B_P) {
    pm_role(hP, embP, p_bias, psP, ps2P, VP, NVB_P, bid - B_STEM, 0, smem_);
  } else if (bid < B_M) {
    const int b = bid - B_P;
    pm_role(hM, embM, m_bias, psM, ps2M, VM, NVB_M, b >> 1, b & 1, smem_);
  } else if (bid < B_M + 2 * gaff) {
    const int b = bid - B_M;
    aff_role(hA, embA, a_bias, asel, arow, aprob, affp, Ta, gaff, b >> 1, b & 1, smem_);
  } else {
    tgt_role(hS, embS, s_bias, tgtS, hP, embP, p_bias, tgtP,
             hM, embM, m_bias, tgtM, tlog, T, bid - B_M - 2 * gaff);
  }
}

// ---------------- per-row combine ----------------
__global__ __launch_bounds__(256) void combine2_kernel(
    const float* __restrict__ psS, const float* __restrict__ ps2S,
    const float* __restrict__ psP, const float* __restrict__ ps2P,
    const float* __restrict__ psM, const float* __restrict__ ps2M,
    const float* __restrict__ tlog,
    float* __restrict__ nll, float* __restrict__ sm, int T) {
  const int lane = threadIdx.x & 63;
  const int wave = threadIdx.x >> 6;
  const int t = blockIdx.x * 4 + wave;
  if (t >= T) return;

  float z = 0.f, s = 0.f;
  if (lane < VCHUNK) {
    z = psS[(size_t)t * VCHUNK + lane];
    s = ps2S[(size_t)t * VCHUNK + lane];
  }
#pragma unroll
  for (int m = 1; m < 64; m <<= 1) { z += __shfl_xor(z, m); s += __shfl_xor(s, m); }
  if (lane == 0) {
    z -= PAD_E;  // pad vocab rows contributed exp2(0)=1 each
    float lz = logf(z);
    nll[t] = lz - tlog[t];
    sm[t]  = (float)VS * lz - s;

    float zP = psP[t], sP = ps2P[t];
    float lzP = logf(zP);
    nll[TPAD + t] = lzP - tlog[TPAD + t];
    sm[TPAD + t]  = (float)VP * lzP - sP;

    float zM = psM[2 * t] + psM[2 * t + 1];
    float sM = ps2M[2 * t] + ps2M[2 * t + 1];
    float lzM = logf(zM);
    nll[2 * TPAD + t] = lzM - tlog[2 * TPAD + t];
    sm[2 * TPAD + t]  = (float)VM * lzM - sM;
  }
}

// ---------------- finalize ----------------
__global__ __launch_bounds__(256) void finalize_kernel(
    const float* __restrict__ nll, const float* __restrict__ sm,
    const float* __restrict__ affp, int naff, float* __restrict__ out, int T, int Ta) {
  __shared__ float red[256];
  const int tid = threadIdx.x;
  float nll_m[3], sm_m[3];
  for (int h2 = 0; h2 < 3; ++h2) {
    float a = 0.f, b = 0.f;
    for (int t = tid; t < T; t += 256) { a += nll[h2 * TPAD + t]; b += sm[h2 * TPAD + t]; }
    red[tid] = a; __syncthreads();
    for (int s = 128; s > 0; s >>= 1) { if (tid < s) red[tid] += red[tid + s]; __syncthreads(); }
    float asum = red[0]; __syncthreads();
    red[tid] = b; __syncthreads();
    for (int s = 128; s > 0; s >>= 1) { if (tid < s) red[tid] += red[tid + s]; __syncthreads(); }
    float bsm = red[0]; __syncthreads();
    nll_m[h2] = asum / (float)T;
    sm_m[h2]  = bsm / (float)T;
  }
  float av = 0.f;
  for (int i = tid; i < naff; i += 256) av += affp[i];
  red[tid] = av; __syncthreads();
  for (int s = 128; s > 0; s >>= 1) { if (tid < s) red[tid] += red[tid + s]; __syncthreads(); }
  if (tid == 0) {
    const float Vv[3] = {(float)VS, (float)VP, (float)VM};
    for (int h2 = 0; h2 < 3; ++h2) {
      float eps_i = 0.1f / (Vv[h2] - 1.f);
      out[h2] = (1.0f - 0.1f - eps_i) * nll_m[h2] + eps_i * sm_m[h2];
      out[4 + h2] = nll_m[h2];
    }
    out[3] = red[0] / ((float)Ta * (float)VA);
  }
}

// ---------------- host launcher ----------------
extern "C" void kernel_launch(void* const* d_in, const int* in_sizes, int n_in,
                              void* d_out, int out_size, void* d_ws, size_t ws_size,
                              hipStream_t stream) {
  const float* tr      = (const float*)d_in[0];
  const float* aprob   = (const float*)d_in[1];
  const int* stems     = (const int*)d_in[2];
  const int* postags   = (const int*)d_in[3];
  const int* morphs    = (const int*)d_in[4];
  const int* hsel      = (const int*)d_in[5];
  const int* tsel      = (const int*)d_in[6];
  const int* asel      = (const int*)d_in[7];
  const float* s_emb = (const float*)d_in[8],  *s_W = (const float*)d_in[9];
  const float* s_b   = (const float*)d_in[10], *s_g = (const float*)d_in[11];
  const float* s_be  = (const float*)d_in[12], *s_bias = (const float*)d_in[13];
  const float* p_emb = (const float*)d_in[14], *p_W = (const float*)d_in[15];
  const float* p_b   = (const float*)d_in[16], *p_g = (const float*)d_in[17];
  const float* p_be  = (const float*)d_in[18], *p_bias = (const float*)d_in[19];
  const float* m_emb = (const float*)d_in[20], *m_W = (const float*)d_in[21];
  const float* m_b   = (const float*)d_in[22], *m_g = (const float*)d_in[23];
  const float* m_be  = (const float*)d_in[24], *m_bias = (const float*)d_in[25];
  const float* a_emb = (const float*)d_in[26], *a_W = (const float*)d_in[27];
  const float* a_b   = (const float*)d_in[28], *a_g = (const float*)d_in[29];
  const float* a_be  = (const float*)d_in[30], *a_bias = (const float*)d_in[31];

  const int T  = in_sizes[5];   // 3576
  const int Ta = in_sizes[7];   // ~2682

  size_t off = 0;
  auto alloc = [&](size_t nbytes) -> char* {
    char* p = (char*)d_ws + off;
    off = (off + nbytes + 255) & ~(size_t)255;
    return p;
  };
  unsigned short* x    = (unsigned short*)alloc((size_t)TPAD * D_MODEL * 2);
  unsigned short* wtS  = (unsigned short*)alloc((size_t)DS_STEM * D_MODEL * 2);
  unsigned short* wtP  = (unsigned short*)alloc((size_t)DS_POS * D_MODEL * 2);
  unsigned short* wtM  = (unsigned short*)alloc((size_t)DS_MORPH * D_MODEL * 2);
  unsigned short* wtA  = (unsigned short*)alloc((size_t)DS_AFF * D_MODEL * 2);
  unsigned short* embS = (unsigned short*)alloc((size_t)VS_PAD * DS_STEM * 2);
  unsigned short* embP = (unsigned short*)alloc((size_t)256 * DS_POS * 2);
  unsigned short* embM = (unsigned short*)alloc((size_t)512 * DS_MORPH * 2);
  unsigned short* embA = (unsigned short*)alloc((size_t)512 * DS_AFF * 2);
  unsigned short* hS   = (unsigned short*)alloc((size_t)TPAD * DS_STEM * 2);
  unsigned short* hP   = (unsigned short*)alloc((size_t)TPAD * DS_POS * 2);
  unsigned short* hM   = (unsigned short*)alloc((size_t)TPAD * DS_MORPH * 2);
  unsigned short* hA   = (unsigned short*)alloc((size_t)TPAD * DS_AFF * 2);
  float* bpadS = (float*)alloc((size_t)VS_PAD * 4);
  float* psS   = (float*)alloc((size_t)TPAD * VCHUNK * 4);
  float* ps2S  = (float*)alloc((size_t)TPAD * VCHUNK * 4);
  float* psP   = (float*)alloc((size_t)TPAD * NVB_P * 4);
  float* ps2P  = (float*)alloc((size_t)TPAD * NVB_P * 4);
  float* psM   = (float*)alloc((size_t)TPAD * NVB_M * 4);
  float* ps2M  = (float*)alloc((size_t)TPAD * NVB_M * 4);
  float* tlog  = (float*)alloc((size_t)3 * TPAD * 4);
  int*   tgtS  = (int*)alloc((size_t)TPAD * 4);
  int*   tgtP  = (int*)alloc((size_t)TPAD * 4);
  int*   tgtM  = (int*)alloc((size_t)TPAD * 4);
  int*   arow  = (int*)alloc((size_t)TPAD * 4);
  float* nllb  = (float*)alloc((size_t)3 * TPAD * 4);
  float* smb   = (float*)alloc((size_t)3 * TPAD * 4);
  float* affp  = (float*)alloc(2048);
  (void)ws_size; (void)n_in; (void)out_size;

  const int gaff = (Ta + 15) / 16;
  const int tgtb = (T + 3) / 4;

  // 1. fused prep: gather(x4) + LDS-tiled W transposes + emb casts
  prep_kernel<<<PREP_C, 256, 0, stream>>>(
      tr, hsel, tsel, asel, stems, postags, morphs, x, tgtS, tgtP, tgtM, arow, T, Ta,
      s_W, p_W, m_W, a_W, wtS, wtP, wtM, wtA,
      s_emb, p_emb, m_emb, a_emb, s_bias, embS, embP, embM, embA, bpadS);
  // 2. all head transforms in one dispatch (256-thread blocks, 64 rows each)
  head_all_kernel<<<dim3(TPAD / 64, 4), 256, 0, stream>>>(
      x, wtS, s_b, s_g, s_be, hS, wtP, p_b, p_g, p_be, hP,
      wtM, m_b, m_g, m_be, hM, wtA, a_b, a_g, a_be, hA);
  // 3. mega: stem stats (2-tile periods, XOR swizzle) + P/M stats + aff + tgt
  mega_stats_kernel<<<B_M + 2 * gaff + tgtb, 256, 0, stream>>>(
      hS, embS, bpadS, psS, ps2S,
      hP, embP, p_bias, psP, ps2P,
      hM, embM, m_bias, psM, ps2M,
      hA, embA, a_bias, asel, arow, aprob, affp,
      s_bias, tgtS, tgtP, tgtM, tlog, T, Ta, gaff);
  // 4. per-row combine + final reduction
  combine2_kernel<<<(T + 3) / 4, 256, 0, stream>>>(psS, ps2S, psP, ps2P, psM, ps2M, tlog, nllb, smb, T);
  finalize_kernel<<<1, 256, 0, stream>>>(nllb, smb, affp, gaff * 2, (float*)d_out, T, Ta);
}